// Round 24
// baseline (7678.008 us; speedup 1.0000x reference)
//
#include <hip/hip_runtime.h>

// Numerics frozen from R20 (PASSED, absmax 0.0039):
//  conv1: (kh,kw,ic) flat FMA chain (OOB taps contribute exact +0);
//  conv2: (kh,kw,ic) 4 panel chains split at k=152/304/456 (tap2:ic24,
//  tap4:ic48, tap7:ic8), joined ((P0+P1)+P2)+P3 then bias; LIF f32
//  two-rounding v+0.5*(x-v); head: ascending-oc conditional-add chain.
// R24: pixel-BITPLANE spikes. Lane = pixel. Mask word (u64, bit=pixel) for
//  (t,tap,ic) sits in an SGPR pair and directly drives
//  v_cndmask_b32 dst,0,w,s[pair] -> 2 VALU/term, no bit extract.
//  kw-shifted plane variants precomputed by k_shift.

#define NB    8
#define HW    128
#define NPIX  (HW*HW)          // 16384
#define NT    5

typedef unsigned long long u64;

// ---------------- W2 [oc][ic][tap] -> Wt2 [oc][tap][ic]
__global__ void k_transpose_w2(const float* __restrict__ W2, float* __restrict__ Wt2) {
    int i = blockIdx.x * 256 + threadIdx.x;      // 36864
    if (i >= 64 * 9 * 64) return;
    int ic = i & 63;
    int tap = (i >> 6) % 9;
    int oc = i / (9 * 64);
    Wt2[i] = W2[(oc * 64 + ic) * 9 + tap];
}

// ---------------- conv1 + LIF1 -> raw pixel bitplanes rawp[b][t][y][xw][ic]
// wave = 64 pixels of one half-row; oc (= conv2 ic) serial 0..63.
__global__ __launch_bounds__(256) void k_conv1_lif1(
    const float* __restrict__ lab, const float* __restrict__ W1,
    const float* __restrict__ b1, const float* __restrict__ tau1,
    u64* __restrict__ rawp)
{
#pragma clang fp contract(off)
    __shared__ float w1s[64 * 27];
    __shared__ float b1s[64];
    {
        int tid = threadIdx.x;
        for (int e = tid; e < 64 * 27; e += 256) w1s[e] = W1[e];
        if (tid < 64) b1s[tid] = b1[tid];
        __syncthreads();
    }
    const int tid = threadIdx.x;
    const int lane = tid & 63;
    const int wid = blockIdx.x * 4 + (tid >> 6); // 2048: (b,y,xw)
    const int b = wid >> 8;
    const int rem = wid & 255;
    const int y = rem >> 1;
    const int xw = rem & 1;
    const int x = xw * 64 + lane;

    // zero-padded 27-neighborhood in registers (static indices)
    float nb[3][3][3];                            // [ic][dy][dx]
#pragma unroll
    for (int ic = 0; ic < 3; ++ic)
#pragma unroll
        for (int dy = 0; dy < 3; ++dy)
#pragma unroll
            for (int dx = 0; dx < 3; ++dx) {
                int yy = y + dy - 1, xx = x + dx - 1;
                float v = 0.f;
                if ((unsigned)yy < (unsigned)HW && (unsigned)xx < (unsigned)HW)
                    v = lab[(b * 3 + ic) * NPIX + yy * HW + xx];
                nb[ic][dy][dx] = v;
            }

    float tauc = fminf(fmaxf(tau1[0], 0.5f), 5.0f);
    const float it = 1.0f / tauc;

    u64 plane[NT];
#pragma unroll
    for (int t = 0; t < NT; ++t) plane[t] = 0ULL;

    for (int oc = 0; oc < 64; ++oc) {            // uniform loop
        const float* w = w1s + oc * 27;
        float acc = 0.f;
#pragma unroll
        for (int kh = 0; kh < 3; ++kh)
#pragma unroll
            for (int kw = 0; kw < 3; ++kw)
#pragma unroll
                for (int ic = 0; ic < 3; ++ic)   // frozen (kh,kw,ic) FMA chain
                    acc = __builtin_fmaf(w[ic * 9 + kh * 3 + kw], nb[ic][kh][kw], acc);
        float xin = acc + b1s[oc];

        float v = 0.f;
#pragma unroll
        for (int t = 0; t < NT; ++t) {
            float d = xin - v;                   // frozen two-rounding LIF
            float m = it * d;
            v = v + m;
            bool s = (v - 0.1f) >= 0.f;
            float vr = s ? 0.f : v;
            vr = fmaxf(vr, -2.f);
            vr = fminf(vr, 2.f);
            v = vr;
            u64 bal = __ballot(s);               // bit i = pixel x0+i
            if (lane == oc) plane[t] = bal;
        }
    }
#pragma unroll
    for (int t = 0; t < NT; ++t)
        rawp[(((size_t)(b * NT + t) * HW + y) * 2 + xw) * 64 + lane] = plane[t];
}

// ---------------- shift: raw planes -> 3 kw-shifted variants
// sbit[(b,t,y,xw)][kw][ic]; bit i of variant kw = spike at pixel x0+i+kw-1.
__global__ __launch_bounds__(256) void k_shift(
    const u64* __restrict__ rawp, u64* __restrict__ sbit)
{
    int g = blockIdx.x * 256 + threadIdx.x;      // 655360 = 8*5*128*2*64
    if (g >= NB * NT * HW * 2 * 64) return;
    int ic = g & 63;
    int xw = (g >> 6) & 1;
    u64 W = rawp[g];
    u64 Wl = xw ? rawp[g - 64] : 0ULL;           // lower-x word, same ic
    u64 Wr = (xw == 0) ? rawp[g + 64] : 0ULL;    // higher-x word
    u64 v0 = (W << 1) | (Wl >> 63);              // kw=0: pixel x-1
    u64 v2 = (W >> 1) | (Wr << 63);              // kw=2: pixel x+1
    size_t base = (size_t)(g >> 6) * 192 + ic;
    sbit[base] = v0;
    sbit[base + 64] = W;
    sbit[base + 128] = v2;
}

// ---------------- conv2 (bitplane cndmask) + LIF2 -> byte spikes
// CH: one 8-ic chunk of one tap into panel PN.
#define CH(KH, KW, CHK, PN)                                                  \
    {                                                                        \
        const u64* mp0 = sbit + ((((size_t)(b * NT + 0) * HW + (y + KH - 1)) * 2 + xw) * 3 + KW) * 64 + (CHK)*8; \
        const u64* mp1 = sbit + ((((size_t)(b * NT + 1) * HW + (y + KH - 1)) * 2 + xw) * 3 + KW) * 64 + (CHK)*8; \
        const u64* mp2 = sbit + ((((size_t)(b * NT + 2) * HW + (y + KH - 1)) * 2 + xw) * 3 + KW) * 64 + (CHK)*8; \
        const u64* mp3 = sbit + ((((size_t)(b * NT + 3) * HW + (y + KH - 1)) * 2 + xw) * 3 + KW) * 64 + (CHK)*8; \
        const u64* mp4 = sbit + ((((size_t)(b * NT + 4) * HW + (y + KH - 1)) * 2 + xw) * 3 + KW) * 64 + (CHK)*8; \
        const uint4* wp = (const uint4*)(Wt2 + oc * 576 + ((KH)*3 + (KW)) * 64 + (CHK)*8); \
        uint4 wA = wp[0], wB = wp[1];                                        \
        unsigned wv8[8] = {wA.x, wA.y, wA.z, wA.w, wB.x, wB.y, wB.z, wB.w};  \
        _Pragma("unroll")                                                    \
        for (int ii = 0; ii < 8; ++ii) {                                     \
            unsigned s0, s1, s2, s3, s4;                                     \
            asm("v_cndmask_b32 %0, 0, %1, %2" : "=v"(s0) : "v"(wv8[ii]), "s"(mp0[ii])); \
            a##PN[0] = a##PN[0] + __uint_as_float(s0);                       \
            asm("v_cndmask_b32 %0, 0, %1, %2" : "=v"(s1) : "v"(wv8[ii]), "s"(mp1[ii])); \
            a##PN[1] = a##PN[1] + __uint_as_float(s1);                       \
            asm("v_cndmask_b32 %0, 0, %1, %2" : "=v"(s2) : "v"(wv8[ii]), "s"(mp2[ii])); \
            a##PN[2] = a##PN[2] + __uint_as_float(s2);                       \
            asm("v_cndmask_b32 %0, 0, %1, %2" : "=v"(s3) : "v"(wv8[ii]), "s"(mp3[ii])); \
            a##PN[3] = a##PN[3] + __uint_as_float(s3);                       \
            asm("v_cndmask_b32 %0, 0, %1, %2" : "=v"(s4) : "v"(wv8[ii]), "s"(mp4[ii])); \
            a##PN[4] = a##PN[4] + __uint_as_float(s4);                       \
        }                                                                    \
    }

#define ROW(KH, BODY) if ((unsigned)(y + KH - 1) < (unsigned)HW) { BODY }

__global__ __launch_bounds__(256) void k_conv2_lif2(
    const u64* __restrict__ sbit, const float* __restrict__ Wt2,
    const float* __restrict__ b2, const float* __restrict__ tau2,
    unsigned char* __restrict__ s2b)
{
#pragma clang fp contract(off)
    const int tid = threadIdx.x;
    const int lane = tid & 63;
    const int wv = __builtin_amdgcn_readfirstlane(tid >> 6);
    const int pos = blockIdx.x;                  // (b,y,xw): 2048
    const int b = pos >> 8;
    const int rem = pos & 255;
    const int y = rem >> 1;
    const int xw = rem & 1;
    const int x = xw * 64 + lane;

    float tauc = fminf(fmaxf(tau2[0], 0.5f), 5.0f);
    const float it = 1.0f / tauc;

    for (int ocl = 0; ocl < 16; ++ocl) {
        const int oc = wv * 16 + ocl;
        const float b2oc = b2[oc];
        float a0[5], a1[5], a2[5], a3[5];        // [panel][t]
#pragma unroll
        for (int t = 0; t < NT; ++t) { a0[t] = 0.f; a1[t] = 0.f; a2[t] = 0.f; a3[t] = 0.f; }

        // taps (kh,kw) ascending, ic ascending; panel splits on chunk bounds
        ROW(0, CH(0,0,0,0) CH(0,0,1,0) CH(0,0,2,0) CH(0,0,3,0) CH(0,0,4,0) CH(0,0,5,0) CH(0,0,6,0) CH(0,0,7,0)
               CH(0,1,0,0) CH(0,1,1,0) CH(0,1,2,0) CH(0,1,3,0) CH(0,1,4,0) CH(0,1,5,0) CH(0,1,6,0) CH(0,1,7,0)
               CH(0,2,0,0) CH(0,2,1,0) CH(0,2,2,0) CH(0,2,3,1) CH(0,2,4,1) CH(0,2,5,1) CH(0,2,6,1) CH(0,2,7,1))
        ROW(1, CH(1,0,0,1) CH(1,0,1,1) CH(1,0,2,1) CH(1,0,3,1) CH(1,0,4,1) CH(1,0,5,1) CH(1,0,6,1) CH(1,0,7,1)
               CH(1,1,0,1) CH(1,1,1,1) CH(1,1,2,1) CH(1,1,3,1) CH(1,1,4,1) CH(1,1,5,1) CH(1,1,6,2) CH(1,1,7,2)
               CH(1,2,0,2) CH(1,2,1,2) CH(1,2,2,2) CH(1,2,3,2) CH(1,2,4,2) CH(1,2,5,2) CH(1,2,6,2) CH(1,2,7,2))
        ROW(2, CH(2,0,0,2) CH(2,0,1,2) CH(2,0,2,2) CH(2,0,3,2) CH(2,0,4,2) CH(2,0,5,2) CH(2,0,6,2) CH(2,0,7,2)
               CH(2,1,0,2) CH(2,1,1,3) CH(2,1,2,3) CH(2,1,3,3) CH(2,1,4,3) CH(2,1,5,3) CH(2,1,6,3) CH(2,1,7,3)
               CH(2,2,0,3) CH(2,2,1,3) CH(2,2,2,3) CH(2,2,3,3) CH(2,2,4,3) CH(2,2,5,3) CH(2,2,6,3) CH(2,2,7,3))

        float v = 0.f;
#pragma unroll
        for (int t = 0; t < NT; ++t) {
            float x2 = (((a0[t] + a1[t]) + a2[t]) + a3[t]) + b2oc;
            float d = x2 - v;                    // frozen LIF chain (t=0: v==0)
            float m = it * d;
            float vp = v + m;
            bool s = (vp - 0.1f) >= 0.f;
            float vr = s ? 0.f : vp;
            vr = fmaxf(vr, -2.f);
            vr = fminf(vr, 2.f);
            v = vr;
            s2b[((size_t)(b * NT + t) * 64 + oc) * NPIX + y * HW + x] = (unsigned char)s;
        }
    }
}

// ---------------- head 1x1 from byte spikes
__global__ __launch_bounds__(256) void k_head(
    const unsigned char* __restrict__ s2b, const float* __restrict__ Wh,
    const float* __restrict__ bh, float* __restrict__ out)
{
#pragma clang fp contract(off)
    __shared__ float whs[192];
    __shared__ float bhs[3];
    {
        int tid = threadIdx.x;
        if (tid < 192) whs[tid] = Wh[tid];
        if (tid < 3) bhs[tid] = bh[tid];
        __syncthreads();
    }
    int g = blockIdx.x * 256 + threadIdx.x;      // (t,b,px)
    int px = g & (NPIX - 1);
    int r = g >> 14;
    int b = r & 7;
    int t = r >> 3;

    const unsigned char* sp = s2b + ((size_t)(b * NT + t) * 64) * NPIX + px;
    float c0 = 0.f, c1 = 0.f, c2 = 0.f;
    for (int oc = 0; oc < 64; ++oc) {            // ascending oc — frozen chain
        if (sp[oc * NPIX]) {
            c0 = c0 + whs[oc];
            c1 = c1 + whs[64 + oc];
            c2 = c2 + whs[128 + oc];
        }
    }
    int obase = ((t * NB + b) * 3) * NPIX + px;
    out[obase] = c0 + bhs[0];
    out[obase + NPIX] = c1 + bhs[1];
    out[obase + 2 * NPIX] = c2 + bhs[2];
}

extern "C" void kernel_launch(void* const* d_in, const int* in_sizes, int n_in,
                              void* d_out, int out_size, void* d_ws, size_t ws_size,
                              hipStream_t stream) {
    const float* lab  = (const float*)d_in[0];
    const float* W1   = (const float*)d_in[1];
    const float* b1   = (const float*)d_in[2];
    const float* tau1 = (const float*)d_in[3];
    const float* W2   = (const float*)d_in[4];
    const float* b2   = (const float*)d_in[5];
    const float* tau2 = (const float*)d_in[6];
    const float* Wh   = (const float*)d_in[7];
    const float* bh   = (const float*)d_in[8];
    float* out = (float*)d_out;

    const size_t SZ_RAW = (size_t)NB * NT * HW * 2 * 64 * 8;     //  5,242,880
    const size_t SZ_SB  = 3 * SZ_RAW;                            // 15,728,640
    const size_t SZ_S2  = (size_t)NB * NT * 64 * NPIX;           // 41,943,040
    const size_t SZ_WT  = 64 * 9 * 64 * 4;                       //    147,456
    if (ws_size < SZ_RAW + SZ_SB + SZ_S2 + SZ_WT) return;

    char* ws = (char*)d_ws;
    u64* rawp          = (u64*)ws;
    u64* sbit          = (u64*)(ws + SZ_RAW);
    unsigned char* s2b = (unsigned char*)(ws + SZ_RAW + SZ_SB);
    float* Wt2         = (float*)(ws + SZ_RAW + SZ_SB + SZ_S2);

    hipLaunchKernelGGL(k_transpose_w2, dim3(144), dim3(256), 0, stream, W2, Wt2);
    hipLaunchKernelGGL(k_conv1_lif1, dim3(512), dim3(256), 0, stream,
                       lab, W1, b1, tau1, rawp);
    hipLaunchKernelGGL(k_shift, dim3(2560), dim3(256), 0, stream, rawp, sbit);
    hipLaunchKernelGGL(k_conv2_lif2, dim3(2048), dim3(256), 0, stream,
                       sbit, Wt2, b2, tau2, s2b);
    hipLaunchKernelGGL(k_head, dim3(NT * NB * NPIX / 256), dim3(256), 0, stream,
                       s2b, Wh, bh, out);
}

// Round 25
// 2047.232 us; speedup vs baseline: 3.7504x; 3.7504x over previous
//
#include <hip/hip_runtime.h>

// Numerics frozen from R20 (PASSED, absmax 0.0039):
//  conv1: (kh,kw,ic) flat FMA chain; conv2: (kh,kw,ic) with 4 panel chains
//  split at k=152/304/456, joined ((P0+P1)+P2)+P3 then bias; LIF f32
//  two-rounding v+0.5*(x-v); head: ascending-oc sequential chain per c.
// R25 = R22 structure (best known: 2488 us) with ONE change in the conv2
// inner term: the uniform -bit selector is computed via the sign-extract
// pattern ((int)(M << (31-k))) >> 31, which the backend matches to a single
// s_bfe_i32 (1 SALU) instead of s_lshr+s_and+s_sub (3 SALU). Per term:
// 1 SALU + 2 VALU (v_and with SGPR src + v_add) = the CU's 1:2 balance.
// w & (-bit) adds exactly w or +0.0 — bit-exact (acc never holds -0.0).

#define NB    8
#define HW    128
#define NPIX  (HW*HW)          // 16384
#define NT    5

// ---------------- W2 [oc][ic][tap] -> Wt [tap][ic][oc]
__global__ void k_transpose_w2(const float* __restrict__ W2, float* __restrict__ Wt) {
    int i = blockIdx.x * 256 + threadIdx.x;      // 36864
    if (i >= 9 * 64 * 64) return;
    int oc = i & 63;
    int ic = (i >> 6) & 63;
    int tap = i >> 12;
    Wt[i] = W2[(oc * 64 + ic) * 9 + tap];
}

// ---------------- conv1 ((kh,kw,ic) flat FMA) + LIF1 -> ballot-packed masks
__global__ __launch_bounds__(256) void k_conv1_lif1(
    const float* __restrict__ lab, const float* __restrict__ W1,
    const float* __restrict__ b1, const float* __restrict__ tau1,
    unsigned long long* __restrict__ smask)
{
#pragma clang fp contract(off)
    __shared__ float w1s[64 * 27];
    __shared__ float b1s[64];
    {
        int tid = threadIdx.x;
        for (int e = tid; e < 64 * 27; e += 256) w1s[e] = W1[e];
        if (tid < 64) b1s[tid] = b1[tid];
        __syncthreads();
    }
    int g = blockIdx.x * 256 + threadIdx.x;      // (b,y,x,oc) — lane = oc
    int oc = g & 63;
    int x = (g >> 6) & (HW - 1);
    int y = (g >> 13) & (HW - 1);
    int b = g >> 20;

    const float* wbase = w1s + oc * 27;
    const float* ibase = lab + b * 3 * NPIX;
    float acc = 0.f;
    for (int kh = 0; kh < 3; ++kh) {             // identical chain to R20
        int yy = y + kh - 1;
        if ((unsigned)yy >= (unsigned)HW) continue;
        for (int kw = 0; kw < 3; ++kw) {
            int xx = x + kw - 1;
            if ((unsigned)xx >= (unsigned)HW) continue;
            const float* px = ibase + yy * HW + xx;
#pragma unroll
            for (int ic = 0; ic < 3; ++ic) {
                acc = __builtin_fmaf(wbase[ic * 9 + kh * 3 + kw], px[ic * NPIX], acc);
            }
        }
    }
    float xin = acc + b1s[oc];

    float tauc = fminf(fmaxf(tau1[0], 0.5f), 5.0f);
    float it = 1.0f / tauc;

    float v = 0.f;
    unsigned bits = 0;
    for (int t = 0; t < NT; ++t) {
        float d = xin - v;
        float m = it * d;
        v = v + m;
        bool s = (v - 0.1f) >= 0.f;
        float vr = s ? 0.f : v;
        vr = fmaxf(vr, -2.f);
        vr = fminf(vr, 2.f);
        v = vr;
        if (s) bits |= (1u << t);
    }
    for (int t = 0; t < NT; ++t) {
        unsigned long long bal = __ballot((bits >> t) & 1);
        if (oc == 0) smask[((size_t)(b * NT + t) * NPIX) + y * HW + x] = bal;
    }
}

// ---------------- conv2 (packed, all t) + LIF2 -> s2 masks
// wave = strip of 8 pixels (y, x0..x0+7), lane = oc. Masks wave-uniform (SGPR).
// Selector: sign-extract pattern -> s_bfe_i32 (1 SALU); v_and + v_add (2 VALU).
#define SEG(IC0, IC1, M, SH, PN)                                        \
    for (int ic = IC0; ic < IC1; ++ic) {                                \
        unsigned wb = wtu[ic * 64];                                     \
        _Pragma("unroll")                                               \
        for (int p = 0; p < 8; ++p) {                                   \
            unsigned nb = (unsigned)(((int)(M[p] << (31 - (ic - SH)))) >> 31); \
            acc[p][PN] = acc[p][PN] + __uint_as_float(wb & nb);         \
        }                                                               \
    }

#define TAP(KH, KW, SEGS) {                                             \
    const int yy = y + KH - 1;                                          \
    const bool vy = (unsigned)yy < (unsigned)HW;                        \
    unsigned Mlo[8], Mhi[8];                                            \
    _Pragma("unroll")                                                   \
    for (int p = 0; p < 8; ++p) {                                       \
        int xx = x0 + KW - 1 + p;                                       \
        unsigned long long mm = (vy && (unsigned)xx < (unsigned)HW)     \
                                ? smb[yy * HW + xx] : 0ULL;             \
        Mlo[p] = (unsigned)mm; Mhi[p] = (unsigned)(mm >> 32);           \
    }                                                                   \
    const unsigned* wtu = (const unsigned*)(Wt + (KH * 3 + KW) * 4096) + oc; \
    SEGS }

__global__ __launch_bounds__(256) void k_conv2_lif2(
    const unsigned long long* __restrict__ smask,
    const float* __restrict__ Wt, const float* __restrict__ b2,
    const float* __restrict__ tau2, unsigned long long* __restrict__ s2m)
{
#pragma clang fp contract(off)
    const int tid = threadIdx.x;
    const int oc = tid & 63;
    const int wid = __builtin_amdgcn_readfirstlane(blockIdx.x * 4 + (tid >> 6));
    const int b = wid >> 11;
    const int rem = wid & 2047;
    const int y = rem >> 4;
    const int x0 = (rem & 15) * 8;

    const float b2oc = b2[oc];
    float tauc = fminf(fmaxf(tau2[0], 0.5f), 5.0f);
    const float it = 1.0f / tauc;

    float v[8];
    for (int t = 0; t < NT; ++t) {
        float acc[8][4];
#pragma unroll
        for (int p = 0; p < 8; ++p) {
            acc[p][0] = 0.f; acc[p][1] = 0.f; acc[p][2] = 0.f; acc[p][3] = 0.f;
        }
        const unsigned long long* smb = smask + (size_t)(b * NT + t) * NPIX;

        // taps in (kh,kw) order; ic ascending; panels split at k=152/304/456
        TAP(0, 0, SEG(0,32,Mlo,0,0)  SEG(32,64,Mhi,32,0))
        TAP(0, 1, SEG(0,32,Mlo,0,0)  SEG(32,64,Mhi,32,0))
        TAP(0, 2, SEG(0,24,Mlo,0,0)  SEG(24,32,Mlo,0,1)  SEG(32,64,Mhi,32,1))
        TAP(1, 0, SEG(0,32,Mlo,0,1)  SEG(32,64,Mhi,32,1))
        TAP(1, 1, SEG(0,32,Mlo,0,1)  SEG(32,48,Mhi,32,1) SEG(48,64,Mhi,32,2))
        TAP(1, 2, SEG(0,32,Mlo,0,2)  SEG(32,64,Mhi,32,2))
        TAP(2, 0, SEG(0,32,Mlo,0,2)  SEG(32,64,Mhi,32,2))
        TAP(2, 1, SEG(0,8,Mlo,0,2)   SEG(8,32,Mlo,0,3)   SEG(32,64,Mhi,32,3))
        TAP(2, 2, SEG(0,32,Mlo,0,3)  SEG(32,64,Mhi,32,3))

        unsigned long long* s2mb = s2m + (size_t)(b * NT + t) * NPIX;
#pragma unroll
        for (int p = 0; p < 8; ++p) {
            float x2 = (((acc[p][0] + acc[p][1]) + acc[p][2]) + acc[p][3]) + b2oc;
            float vp = (t == 0) ? 0.f : v[p];
            float d = x2 - vp;
            float m = it * d;
            vp = vp + m;
            bool s = (vp - 0.1f) >= 0.f;
            float vr = s ? 0.f : vp;
            vr = fmaxf(vr, -2.f);
            vr = fminf(vr, 2.f);
            v[p] = vr;
            unsigned long long bal = __ballot(s);
            if (oc == 0) s2mb[y * HW + x0 + p] = bal;
        }
    }
}

// ---------------- head 1x1 from packed s2 masks
__global__ __launch_bounds__(256) void k_head(
    const unsigned long long* __restrict__ s2m, const float* __restrict__ Wh,
    const float* __restrict__ bh, float* __restrict__ out)
{
#pragma clang fp contract(off)
    __shared__ float whs[192];
    __shared__ float bhs[3];
    {
        int tid = threadIdx.x;
        if (tid < 192) whs[tid] = Wh[tid];
        if (tid < 3) bhs[tid] = bh[tid];
        __syncthreads();
    }
    int g = blockIdx.x * 256 + threadIdx.x;      // (t,b,px): 5*8*16384
    int px = g & (NPIX - 1);
    int r = g >> 14;
    int b = r & 7;
    int t = r >> 3;

    unsigned long long m = s2m[(size_t)(b * NT + t) * NPIX + px];
    unsigned mlo = (unsigned)m, mhi = (unsigned)(m >> 32);
    float c0 = 0.f, c1 = 0.f, c2 = 0.f;
    for (int oc = 0; oc < 32; ++oc) {            // ascending oc — frozen chain
        unsigned bit = (mlo >> oc) & 1u;
        if (bit) { c0 = c0 + whs[oc]; c1 = c1 + whs[64 + oc]; c2 = c2 + whs[128 + oc]; }
    }
    for (int oc = 32; oc < 64; ++oc) {
        unsigned bit = (mhi >> (oc - 32)) & 1u;
        if (bit) { c0 = c0 + whs[oc]; c1 = c1 + whs[64 + oc]; c2 = c2 + whs[128 + oc]; }
    }
    int obase = ((t * NB + b) * 3) * NPIX + px;
    out[obase] = c0 + bhs[0];
    out[obase + NPIX] = c1 + bhs[1];
    out[obase + 2 * NPIX] = c2 + bhs[2];
}

extern "C" void kernel_launch(void* const* d_in, const int* in_sizes, int n_in,
                              void* d_out, int out_size, void* d_ws, size_t ws_size,
                              hipStream_t stream) {
    const float* lab  = (const float*)d_in[0];
    const float* W1   = (const float*)d_in[1];
    const float* b1   = (const float*)d_in[2];
    const float* tau1 = (const float*)d_in[3];
    const float* W2   = (const float*)d_in[4];
    const float* b2   = (const float*)d_in[5];
    const float* tau2 = (const float*)d_in[6];
    const float* Wh   = (const float*)d_in[7];
    const float* bh   = (const float*)d_in[8];
    float* out = (float*)d_out;

    // ws: smask 5.25MB | s2mask 5.25MB | Wt 147KB
    const size_t SZ_SM = (size_t)NB * NT * NPIX * 8;         // 5,242,880
    const size_t SZ_WT = 9 * 64 * 64 * 4;                    //   147,456
    if (ws_size < 2 * SZ_SM + SZ_WT) return;

    char* ws = (char*)d_ws;
    unsigned long long* smask = (unsigned long long*)ws;
    unsigned long long* s2m   = (unsigned long long*)(ws + SZ_SM);
    float* Wt                 = (float*)(ws + 2 * SZ_SM);

    hipLaunchKernelGGL(k_transpose_w2, dim3(144), dim3(256), 0, stream, W2, Wt);
    hipLaunchKernelGGL(k_conv1_lif1, dim3(NB * 64 * NPIX / 256), dim3(256), 0, stream,
                       lab, W1, b1, tau1, smask);
    hipLaunchKernelGGL(k_conv2_lif2, dim3(4096), dim3(256), 0, stream,
                       smask, Wt, b2, tau2, s2m);
    hipLaunchKernelGGL(k_head, dim3(NT * NB * NPIX / 256), dim3(256), 0, stream,
                       s2m, Wh, bh, out);
}